// Round 16
// baseline (1308.165 us; speedup 1.0000x reference)
//
#include <hip/hip_runtime.h>
#include <hip/hip_cooperative_groups.h>
namespace cg = cooperative_groups;

#define Nn 50000
#define Dd 64
#define Ee 800000
#define Ll 3
#define Rr 2
#define Gg 128
#define Cc 10
#define NR (Nn * Rr)
#define NBc 98                 // 1024-element scan chunks over NR
#define NT (Nn / 16)           // 3125 tasks

// fallback k_setup block ranges (exact multiples of 256)
#define CVT_B  3125
#define PREP_B 240
#define HIST_B 3125

typedef __attribute__((ext_vector_type(8))) short short8;
typedef __attribute__((ext_vector_type(4))) float f32x4;

__device__ __forceinline__ unsigned short bf16_rne(float x) {
  unsigned u = __float_as_uint(x);
  unsigned r = u + 0x7fffu + ((u >> 16) & 1u);
  return (unsigned short)(r >> 16);
}
__device__ __forceinline__ float bf16_tof(unsigned short b) {
  return __uint_as_float(((unsigned)b) << 16);
}
__device__ __forceinline__ void acc8(float* z, uint4 u) {
  z[0] += __uint_as_float(u.x << 16);
  z[1] += __uint_as_float(u.x & 0xffff0000u);
  z[2] += __uint_as_float(u.y << 16);
  z[3] += __uint_as_float(u.y & 0xffff0000u);
  z[4] += __uint_as_float(u.z << 16);
  z[5] += __uint_as_float(u.z & 0xffff0000u);
  z[6] += __uint_as_float(u.w << 16);
  z[7] += __uint_as_float(u.w & 0xffff0000u);
}

#define WOFF(m, c, ks) ((size_t)(m)*4096 + (size_t)(c)*64 + (ks)*32 + koff)

// ---------------- one GIN layer task (identical math to round 14) -----------
__device__ __forceinline__ void layer_task(
    int task, const unsigned short* hb, unsigned short* hnb, int l,
    const int* offs, const int* counts, const int* elist,
    const unsigned short* wtHi, const unsigned short* wtLo,
    const float* selfb, const float* eps, const float* b1, const float* b2,
    unsigned short* tbh, unsigned short* tbl)
{
  float* xfer = (float*)tbh;            // aliased: tb dead by combine time
  const int wave = threadIdx.x >> 6;    // = relation r
  const int lane = threadIdx.x & 63;
  const int r = wave;
  const int idx15 = lane & 15;
  const int kg = lane >> 4;
  const int koff = kg * 8;
  const int nodeA = task * 16 + idx15;
  unsigned short* tw_h = tbh + wave * (16 * 72);
  unsigned short* tw_l = tbl + wave * (16 * 72);

  uint4 u0, u1;
  {
    const unsigned short* hp = &hb[(size_t)nodeA * 64 + koff];
    u0 = *(const uint4*)(hp);
    u1 = *(const uint4*)(hp + 32);
  }
  float f[2][8];
  f[0][0] = __uint_as_float(u0.x << 16); f[0][1] = __uint_as_float(u0.x & 0xffff0000u);
  f[0][2] = __uint_as_float(u0.y << 16); f[0][3] = __uint_as_float(u0.y & 0xffff0000u);
  f[0][4] = __uint_as_float(u0.z << 16); f[0][5] = __uint_as_float(u0.z & 0xffff0000u);
  f[0][6] = __uint_as_float(u0.w << 16); f[0][7] = __uint_as_float(u0.w & 0xffff0000u);
  f[1][0] = __uint_as_float(u1.x << 16); f[1][1] = __uint_as_float(u1.x & 0xffff0000u);
  f[1][2] = __uint_as_float(u1.y << 16); f[1][3] = __uint_as_float(u1.y & 0xffff0000u);
  f[1][4] = __uint_as_float(u1.z << 16); f[1][5] = __uint_as_float(u1.z & 0xffff0000u);
  f[1][6] = __uint_as_float(u1.w << 16); f[1][7] = __uint_as_float(u1.w & 0xffff0000u);

  const unsigned short* whi = wtHi + (size_t)l * 5 * 4096;
  const unsigned short* wlo = wtLo + (size_t)l * 5 * 4096;
  const int m1 = 1 + 2 * r, m2 = 2 + 2 * r;
  const float er = 1.0f + eps[l * Rr + r];

  float za[2][8];
#pragma unroll
  for (int ks = 0; ks < 2; ++ks)
#pragma unroll
    for (int jj = 0; jj < 8; ++jj) za[ks][jj] = 0.0f;
  {
    const int aidx = r * Nn + nodeA;
    const int jb = offs[aidx];
    const int je = jb + counts[aidx];
    int j = jb;
    if (j + 7 < je) {
      int4 ec0 = *(const int4*)&elist[j];
      int4 ec1 = *(const int4*)&elist[j + 4];
      for (; j + 7 < je; j += 8) {
        int4 en0 = *(const int4*)&elist[j + 8];
        int4 en1 = *(const int4*)&elist[j + 12];
        const unsigned short* q0 = &hb[(size_t)ec0.x * 64 + koff];
        const unsigned short* q1 = &hb[(size_t)ec0.y * 64 + koff];
        const unsigned short* q2 = &hb[(size_t)ec0.z * 64 + koff];
        const unsigned short* q3 = &hb[(size_t)ec0.w * 64 + koff];
        const unsigned short* q4 = &hb[(size_t)ec1.x * 64 + koff];
        const unsigned short* q5 = &hb[(size_t)ec1.y * 64 + koff];
        const unsigned short* q6 = &hb[(size_t)ec1.z * 64 + koff];
        const unsigned short* q7 = &hb[(size_t)ec1.w * 64 + koff];
        const uint4 a0 = *(const uint4*)(q0);
        const uint4 a1 = *(const uint4*)(q1);
        const uint4 a2 = *(const uint4*)(q2);
        const uint4 a3 = *(const uint4*)(q3);
        const uint4 a4 = *(const uint4*)(q4);
        const uint4 a5 = *(const uint4*)(q5);
        const uint4 a6 = *(const uint4*)(q6);
        const uint4 a7 = *(const uint4*)(q7);
        const uint4 b0 = *(const uint4*)(q0 + 32);
        const uint4 b1q = *(const uint4*)(q1 + 32);
        const uint4 b2q = *(const uint4*)(q2 + 32);
        const uint4 b3 = *(const uint4*)(q3 + 32);
        const uint4 b4 = *(const uint4*)(q4 + 32);
        const uint4 b5 = *(const uint4*)(q5 + 32);
        const uint4 b6 = *(const uint4*)(q6 + 32);
        const uint4 b7 = *(const uint4*)(q7 + 32);
        acc8(za[0], a0); acc8(za[0], a1); acc8(za[0], a2); acc8(za[0], a3);
        acc8(za[0], a4); acc8(za[0], a5); acc8(za[0], a6); acc8(za[0], a7);
        acc8(za[1], b0); acc8(za[1], b1q); acc8(za[1], b2q); acc8(za[1], b3);
        acc8(za[1], b4); acc8(za[1], b5); acc8(za[1], b6); acc8(za[1], b7);
        ec0 = en0; ec1 = en1;
      }
    }
    if (j + 3 < je) {
      int4 ec = *(const int4*)&elist[j];
      const unsigned short* q0 = &hb[(size_t)ec.x * 64 + koff];
      const unsigned short* q1 = &hb[(size_t)ec.y * 64 + koff];
      const unsigned short* q2 = &hb[(size_t)ec.z * 64 + koff];
      const unsigned short* q3 = &hb[(size_t)ec.w * 64 + koff];
      const uint4 a0 = *(const uint4*)(q0);
      const uint4 a1 = *(const uint4*)(q1);
      const uint4 a2 = *(const uint4*)(q2);
      const uint4 a3 = *(const uint4*)(q3);
      const uint4 b0 = *(const uint4*)(q0 + 32);
      const uint4 b1q = *(const uint4*)(q1 + 32);
      const uint4 b2q = *(const uint4*)(q2 + 32);
      const uint4 b3 = *(const uint4*)(q3 + 32);
      acc8(za[0], a0); acc8(za[0], a1); acc8(za[0], a2); acc8(za[0], a3);
      acc8(za[1], b0); acc8(za[1], b1q); acc8(za[1], b2q); acc8(za[1], b3);
      j += 4;
    }
    for (; j < je; ++j) {
      const unsigned short* q = &hb[(size_t)elist[j] * 64 + koff];
      const uint4 a = *(const uint4*)(q);
      const uint4 b = *(const uint4*)(q + 32);
      acc8(za[0], a); acc8(za[1], b);
    }
  }

  short8 zhi[2], zlo[2];
#pragma unroll
  for (int ks = 0; ks < 2; ++ks)
#pragma unroll
    for (int jj = 0; jj < 8; ++jj) {
      float zf = er * f[ks][jj] + za[ks][jj];
      unsigned short hb2 = bf16_rne(zf);
      zhi[ks][jj] = (short)hb2;
      zlo[ks][jj] = (short)bf16_rne(zf - bf16_tof(hb2));
    }

  f32x4 tacc[4];
#pragma unroll
  for (int cb = 0; cb < 4; ++cb) {
    float bi = b1[((size_t)l * 2 + r) * 64 + cb * 16 + idx15];
    tacc[cb] = (f32x4){bi, bi, bi, bi};
  }
#pragma unroll
  for (int cb = 0; cb < 4; ++cb) {
    int c = cb * 16 + idx15;
#pragma unroll
    for (int ks = 0; ks < 2; ++ks) {
      const short8 bh = *(const short8*)&whi[WOFF(m1, c, ks)];
      const short8 bl = *(const short8*)&wlo[WOFF(m1, c, ks)];
      tacc[cb] = __builtin_amdgcn_mfma_f32_16x16x32_bf16(zhi[ks], bh, tacc[cb], 0, 0, 0);
      tacc[cb] = __builtin_amdgcn_mfma_f32_16x16x32_bf16(zhi[ks], bl, tacc[cb], 0, 0, 0);
      tacc[cb] = __builtin_amdgcn_mfma_f32_16x16x32_bf16(zlo[ks], bh, tacc[cb], 0, 0, 0);
    }
  }
#pragma unroll
  for (int cb = 0; cb < 4; ++cb)
#pragma unroll
    for (int q = 0; q < 4; ++q) {
      float tv = fmaxf(tacc[cb][q], 0.0f);
      unsigned short hb2 = bf16_rne(tv);
      tw_h[(kg * 4 + q) * 72 + cb * 16 + idx15] = hb2;
      tw_l[(kg * 4 + q) * 72 + cb * 16 + idx15] = bf16_rne(tv - bf16_tof(hb2));
    }
  asm volatile("s_waitcnt lgkmcnt(0)" ::: "memory");
  __builtin_amdgcn_sched_barrier(0);
  short8 thi[2], tlo[2];
#pragma unroll
  for (int ks = 0; ks < 2; ++ks) {
    thi[ks] = *(const short8*)&tw_h[idx15 * 72 + ks * 32 + koff];
    tlo[ks] = *(const short8*)&tw_l[idx15 * 72 + ks * 32 + koff];
  }

  f32x4 facc[4];
#pragma unroll
  for (int cb = 0; cb < 4; ++cb) {
    int c = cb * 16 + idx15;
    float bi = b2[((size_t)l * 2 + r) * 64 + c];
    if (wave == 1) bi += selfb[l * 64 + c];
    facc[cb] = (f32x4){bi, bi, bi, bi};
  }
#pragma unroll
  for (int cb = 0; cb < 4; ++cb) {
    int c = cb * 16 + idx15;
#pragma unroll
    for (int ks = 0; ks < 2; ++ks) {
      const short8 bh = *(const short8*)&whi[WOFF(m2, c, ks)];
      const short8 bl = *(const short8*)&wlo[WOFF(m2, c, ks)];
      facc[cb] = __builtin_amdgcn_mfma_f32_16x16x32_bf16(thi[ks], bh, facc[cb], 0, 0, 0);
      facc[cb] = __builtin_amdgcn_mfma_f32_16x16x32_bf16(thi[ks], bl, facc[cb], 0, 0, 0);
      facc[cb] = __builtin_amdgcn_mfma_f32_16x16x32_bf16(tlo[ks], bh, facc[cb], 0, 0, 0);
    }
  }
  if (wave == 1) {
    short8 ahi[2];
    ahi[0][0] = (short)(u0.x & 0xffff); ahi[0][1] = (short)(u0.x >> 16);
    ahi[0][2] = (short)(u0.y & 0xffff); ahi[0][3] = (short)(u0.y >> 16);
    ahi[0][4] = (short)(u0.z & 0xffff); ahi[0][5] = (short)(u0.z >> 16);
    ahi[0][6] = (short)(u0.w & 0xffff); ahi[0][7] = (short)(u0.w >> 16);
    ahi[1][0] = (short)(u1.x & 0xffff); ahi[1][1] = (short)(u1.x >> 16);
    ahi[1][2] = (short)(u1.y & 0xffff); ahi[1][3] = (short)(u1.y >> 16);
    ahi[1][4] = (short)(u1.z & 0xffff); ahi[1][5] = (short)(u1.z >> 16);
    ahi[1][6] = (short)(u1.w & 0xffff); ahi[1][7] = (short)(u1.w >> 16);
#pragma unroll
    for (int cb = 0; cb < 4; ++cb) {
      int c = cb * 16 + idx15;
#pragma unroll
      for (int ks = 0; ks < 2; ++ks) {
        const short8 bh = *(const short8*)&whi[WOFF(0, c, ks)];
        const short8 bl = *(const short8*)&wlo[WOFF(0, c, ks)];
        facc[cb] = __builtin_amdgcn_mfma_f32_16x16x32_bf16(ahi[ks], bh, facc[cb], 0, 0, 0);
        facc[cb] = __builtin_amdgcn_mfma_f32_16x16x32_bf16(ahi[ks], bl, facc[cb], 0, 0, 0);
      }
    }
  }
  __syncthreads();                      // all tb reads done -> safe to alias
  if (wave == 1) {
#pragma unroll
    for (int cb = 0; cb < 4; ++cb)
#pragma unroll
      for (int q = 0; q < 4; ++q)
        xfer[(kg * 4 + q) * 65 + cb * 16 + idx15] = facc[cb][q];
  }
  __syncthreads();
  if (wave == 0) {
#pragma unroll
    for (int cb = 0; cb < 4; ++cb)
#pragma unroll
      for (int q = 0; q < 4; ++q) {
        int row = kg * 4 + q, col = cb * 16 + idx15;
        float v = facc[cb][q] + xfer[row * 65 + col];
        hnb[((size_t)task * 16 + row) * 64 + col] = bf16_rne(v);
      }
  }
  __syncthreads();                      // xfer reads done before buffer reuse
}

// ================= cooperative mega-kernel (grid-stride, any grid) ==========
__global__ __launch_bounds__(128, 4) void k_mega(
    const float* x, const int* src, const int* dst, const int* et,
    const int* batch,
    const float* selfW, const float* W1, const float* W2,
    const float* selfb, const float* eps, const float* b1, const float* b2,
    const float* l1W, const float* l1b, const float* l2W, const float* l2b,
    unsigned short* hb0, unsigned short* hb1,
    unsigned short* wtHi, unsigned short* wtLo,
    int* counts, int* offs, int* cursor, int* btot, int* elist,
    float* out)
{
  __shared__ __align__(16) unsigned short tbh[2 * 16 * 72];
  __shared__ __align__(16) unsigned short tbl[2 * 16 * 72];
  cg::grid_group grid = cg::this_grid();
  const int B = blockIdx.x;
  const int T = threadIdx.x;
  const int gi = B * 128 + T;
  const int stride = gridDim.x * 128;

  // ---- P1: x->bf16 shadow | weight split-bf16 prep | histogram -------------
  for (int i = gi; i < Nn * Dd / 4; i += stride) {
    const float4 v = *(const float4*)&x[(size_t)i * 4];
    ushort4 o;
    o.x = bf16_rne(v.x); o.y = bf16_rne(v.y);
    o.z = bf16_rne(v.z); o.w = bf16_rne(v.w);
    *(ushort4*)&hb0[(size_t)i * 4] = o;
  }
  for (int i = gi; i < Ll * 5 * 4096; i += stride) {
    int l = i / (5 * 4096);
    int rem = i - l * 5 * 4096;
    int m = rem >> 12;
    int e = rem & 4095;
    int k = e >> 6, c = e & 63;
    const float* p;
    if (m == 0)      p = selfW + (size_t)l * 4096;
    else if (m == 1) p = W1 + ((size_t)l * 2 + 0) * 4096;
    else if (m == 2) p = W2 + ((size_t)l * 2 + 0) * 4096;
    else if (m == 3) p = W1 + ((size_t)l * 2 + 1) * 4096;
    else             p = W2 + ((size_t)l * 2 + 1) * 4096;
    float w = p[e];
    unsigned short hi = bf16_rne(w);
    unsigned short lo = bf16_rne(w - bf16_tof(hi));
    size_t o = ((size_t)(l * 5 + m) * 64 + c) * 64 + k;
    wtHi[o] = hi;
    wtLo[o] = lo;
  }
  for (int e = gi; e < Ee; e += stride)
    atomicAdd(&counts[et[e] * Nn + dst[e]], 1);
  grid.sync();

  // ---- P2: chunk-local scan of padded counts (blocks 0..97) ----------------
  if (B < NBc) {
    int* ts = (int*)tbh;
    int base = B * 1024 + T * 8;
    int inc[8];
    int s = 0;
#pragma unroll
    for (int k = 0; k < 8; ++k) {
      int idx = base + k;
      int v = (idx < NR) ? ((counts[idx] + 3) & ~3) : 0;
      s += v;
      inc[k] = s;
    }
    ts[T] = s;
    __syncthreads();
    for (int d = 1; d < 128; d <<= 1) {
      int t2 = (T >= d) ? ts[T - d] : 0;
      __syncthreads();
      ts[T] += t2;
      __syncthreads();
    }
    int texcl = (T > 0) ? ts[T - 1] : 0;
#pragma unroll
    for (int k = 0; k < 8; ++k) {
      int idx = base + k;
      if (idx < NR) offs[idx + 1] = texcl + inc[k];
    }
    if (T == 127) btot[B] = ts[127];
  }
  grid.sync();

  // ---- P3: global fixup + cursor init (blocks 0..97) -----------------------
  if (B < NBc) {
    int* bs = (int*)tbh;
    bs[T] = (T < NBc) ? btot[T] : 0;
    __syncthreads();
    for (int d = 1; d < 128; d <<= 1) {
      int t2 = (T >= d) ? bs[T - d] : 0;
      __syncthreads();
      bs[T] += t2;
      __syncthreads();
    }
    int myb = (B > 0) ? bs[B - 1] : 0;
    int base = B * 1024 + T * 8;
#pragma unroll
    for (int k = 0; k < 8; ++k) {
      int idx = base + k;
      if (idx < NR) {
        int o = offs[idx + 1] + myb;
        offs[idx + 1] = o;
        cursor[idx] = o - ((counts[idx] + 3) & ~3);
      }
    }
    if (B == 0 && T == 0) offs[0] = 0;
  }
  grid.sync();

  // ---- P4: fill padded CSR --------------------------------------------------
  for (int e = gi; e < Ee; e += stride) {
    int pos = atomicAdd(&cursor[et[e] * Nn + dst[e]], 1);
    elist[pos] = src[e];
  }
  grid.sync();

  // ---- layers (grid-stride over tasks) --------------------------------------
  for (int t = B; t < NT; t += gridDim.x)
    layer_task(t, hb0, hb1, 0, offs, counts, elist, wtHi, wtLo, selfb, eps, b1, b2, tbh, tbl);
  grid.sync();
  for (int t = B; t < NT; t += gridDim.x)
    layer_task(t, hb1, hb0, 1, offs, counts, elist, wtHi, wtLo, selfb, eps, b1, b2, tbh, tbl);
  grid.sync();
  for (int t = B; t < NT; t += gridDim.x)
    layer_task(t, hb0, hb1, 2, offs, counts, elist, wtHi, wtLo, selfb, eps, b1, b2, tbh, tbl);
  grid.sync();

  // ---- pool + head (blocks 0..127, 2 waves each) ----------------------------
  if (B < Gg) {
    float* part = (float*)tbh;          // [2][64]
    int g = B;
    int wave = T >> 6;
    int lane = T & 63;
    int lo = 0, hi = Nn;
    while (lo < hi) { int mid = (lo + hi) >> 1; if (batch[mid] < g) lo = mid + 1; else hi = mid; }
    int start = lo;
    hi = Nn;
    while (lo < hi) { int mid = (lo + hi) >> 1; if (batch[mid] < g + 1) lo = mid + 1; else hi = mid; }
    int end = lo;

    float acc = 0.0f;
    for (int i = start + wave; i < end; i += 2)
      acc += bf16_tof(hb1[(size_t)i * 64 + lane]);
    part[wave * 64 + lane] = acc;
    __syncthreads();
    if (wave == 0) {
      float s = part[lane] + part[64 + lane];
      float p = s / fmaxf((float)(end - start), 1.0f);
      float t = l1b[lane];
#pragma unroll
      for (int k = 0; k < Dd; ++k)
        t += __shfl(p, k, 64) * l1W[k * Dd + lane];
      t = fmaxf(t, 0.0f);
      float o = (lane < Cc) ? l2b[lane] : 0.0f;
#pragma unroll
      for (int k = 0; k < Dd; ++k) {
        float w = (lane < Cc) ? l2W[k * Cc + lane] : 0.0f;
        o += __shfl(t, k, 64) * w;
      }
      if (lane < Cc) out[(size_t)g * Cc + lane] = o;
    }
  }
}

// ================= fallback path (round-14 proven sequence) =================
__global__ __launch_bounds__(256) void k_setup(
    const float* __restrict__ x, unsigned short* __restrict__ hb,
    const float* __restrict__ selfW, const float* __restrict__ W1,
    const float* __restrict__ W2, unsigned short* __restrict__ wtHi,
    unsigned short* __restrict__ wtLo,
    const int* __restrict__ dst, const int* __restrict__ et,
    int* __restrict__ counts)
{
  int b = blockIdx.x;
  if (b < CVT_B) {
    int i = b * 256 + threadIdx.x;
    const float4 v = *(const float4*)&x[(size_t)i * 4];
    ushort4 o;
    o.x = bf16_rne(v.x); o.y = bf16_rne(v.y);
    o.z = bf16_rne(v.z); o.w = bf16_rne(v.w);
    *(ushort4*)&hb[(size_t)i * 4] = o;
  } else if (b < CVT_B + PREP_B) {
    int i = (b - CVT_B) * 256 + threadIdx.x;
    int l = i / (5 * 4096);
    int rem = i - l * 5 * 4096;
    int m = rem >> 12;
    int e = rem & 4095;
    int k = e >> 6, c = e & 63;
    const float* p;
    if (m == 0)      p = selfW + (size_t)l * 4096;
    else if (m == 1) p = W1 + ((size_t)l * 2 + 0) * 4096;
    else if (m == 2) p = W2 + ((size_t)l * 2 + 0) * 4096;
    else if (m == 3) p = W1 + ((size_t)l * 2 + 1) * 4096;
    else             p = W2 + ((size_t)l * 2 + 1) * 4096;
    float w = p[e];
    unsigned short hi = bf16_rne(w);
    unsigned short lo = bf16_rne(w - bf16_tof(hi));
    size_t o = ((size_t)(l * 5 + m) * 64 + c) * 64 + k;
    wtHi[o] = hi;
    wtLo[o] = lo;
  } else {
    int e = (b - CVT_B - PREP_B) * 256 + threadIdx.x;
    atomicAdd(&counts[et[e] * Nn + dst[e]], 1);
  }
}

__global__ __launch_bounds__(1024) void k_scan1(
    const int* __restrict__ counts, int* __restrict__ offs,
    int* __restrict__ btot)
{
  __shared__ int s[1024];
  int i = blockIdx.x * 1024 + threadIdx.x;
  int v = (i < NR) ? ((counts[i] + 3) & ~3) : 0;
  s[threadIdx.x] = v;
  __syncthreads();
#pragma unroll
  for (int d = 1; d < 1024; d <<= 1) {
    int t = (threadIdx.x >= d) ? s[threadIdx.x - d] : 0;
    __syncthreads();
    s[threadIdx.x] += t;
    __syncthreads();
  }
  if (i < NR) offs[i + 1] = s[threadIdx.x];
  if (threadIdx.x == 1023) btot[blockIdx.x] = s[1023];
}

__global__ __launch_bounds__(1024) void k_scan3(
    const int* __restrict__ counts, const int* __restrict__ btot,
    int* __restrict__ offs, int* __restrict__ cursor)
{
  __shared__ int bs[128];
  int v = (threadIdx.x < NBc) ? btot[threadIdx.x] : 0;
  if (threadIdx.x < 128) bs[threadIdx.x] = v;
  __syncthreads();
#pragma unroll
  for (int d = 1; d < 128; d <<= 1) {
    int t = (threadIdx.x >= d && threadIdx.x < 128) ? bs[threadIdx.x - d] : 0;
    __syncthreads();
    if (threadIdx.x < 128) bs[threadIdx.x] += t;
    __syncthreads();
  }
  int myb = (blockIdx.x == 0) ? 0 : bs[blockIdx.x - 1];
  int i = blockIdx.x * 1024 + threadIdx.x;
  if (i >= NR) return;
  int o = offs[i + 1] + myb;
  offs[i + 1] = o;
  cursor[i] = o - ((counts[i] + 3) & ~3);
  if (i == 0) offs[0] = 0;
}

__global__ __launch_bounds__(256) void k_fill(
    const int* __restrict__ src, const int* __restrict__ dst,
    const int* __restrict__ et, int* __restrict__ cursor,
    int* __restrict__ elist)
{
  int e = blockIdx.x * 256 + threadIdx.x;
  if (e >= Ee) return;
  int pos = atomicAdd(&cursor[et[e] * Nn + dst[e]], 1);
  elist[pos] = src[e];
}

__global__ __launch_bounds__(128, 4) void k_upd(
    const unsigned short* hb, const int* offs, const int* counts,
    const int* elist, const unsigned short* wtHi, const unsigned short* wtLo,
    const float* selfb, const float* eps, const float* b1, const float* b2,
    unsigned short* hnb, int l)
{
  __shared__ __align__(16) unsigned short tbh[2 * 16 * 72];
  __shared__ __align__(16) unsigned short tbl[2 * 16 * 72];
  layer_task(blockIdx.x, hb, hnb, l, offs, counts, elist, wtHi, wtLo,
             selfb, eps, b1, b2, tbh, tbl);
}

__global__ __launch_bounds__(512) void k_poolhead(
    const unsigned short* __restrict__ hb, const int* __restrict__ batch,
    const float* __restrict__ l1W, const float* __restrict__ l1b,
    const float* __restrict__ l2W, const float* __restrict__ l2b,
    float* __restrict__ out)
{
  __shared__ float part[8][64];
  int g = blockIdx.x;
  int wave = threadIdx.x >> 6;
  int lane = threadIdx.x & 63;
  int lo = 0, hi = Nn;
  while (lo < hi) { int mid = (lo + hi) >> 1; if (batch[mid] < g) lo = mid + 1; else hi = mid; }
  int start = lo;
  hi = Nn;
  while (lo < hi) { int mid = (lo + hi) >> 1; if (batch[mid] < g + 1) lo = mid + 1; else hi = mid; }
  int end = lo;

  float acc = 0.0f;
  for (int i = start + wave; i < end; i += 8)
    acc += bf16_tof(hb[(size_t)i * 64 + lane]);
  part[wave][lane] = acc;
  __syncthreads();
  if (wave == 0) {
    float s = 0.0f;
#pragma unroll
    for (int w = 0; w < 8; ++w) s += part[w][lane];
    float p = s / fmaxf((float)(end - start), 1.0f);
    float t = l1b[lane];
#pragma unroll
    for (int k = 0; k < Dd; ++k)
      t += __shfl(p, k, 64) * l1W[k * Dd + lane];
    t = fmaxf(t, 0.0f);
    float o = (lane < Cc) ? l2b[lane] : 0.0f;
#pragma unroll
    for (int k = 0; k < Dd; ++k) {
      float w = (lane < Cc) ? l2W[k * Cc + lane] : 0.0f;
      o += __shfl(t, k, 64) * w;
    }
    if (lane < Cc) out[(size_t)g * Cc + lane] = o;
  }
}

extern "C" void kernel_launch(void* const* d_in, const int* in_sizes, int n_in,
                              void* d_out, int out_size, void* d_ws, size_t ws_size,
                              hipStream_t stream)
{
  const float* x     = (const float*)d_in[0];
  const int*   ei    = (const int*)d_in[1];
  const int*   et    = (const int*)d_in[2];
  const int*   batch = (const int*)d_in[3];
  const float* selfW = (const float*)d_in[4];
  const float* selfb = (const float*)d_in[5];
  const float* eps   = (const float*)d_in[6];
  const float* W1    = (const float*)d_in[7];
  const float* b1    = (const float*)d_in[8];
  const float* W2    = (const float*)d_in[9];
  const float* b2    = (const float*)d_in[10];
  const float* l1W   = (const float*)d_in[11];
  const float* l1b   = (const float*)d_in[12];
  const float* l2W   = (const float*)d_in[13];
  const float* l2b   = (const float*)d_in[14];
  float* out = (float*)d_out;

  unsigned short* hb0 = (unsigned short*)d_ws;
  unsigned short* hb1 = hb0 + (size_t)Nn * Dd;
  unsigned short* wtHi = hb1 + (size_t)Nn * Dd;
  unsigned short* wtLo = wtHi + (size_t)Ll * 5 * 4096;
  int* counts = (int*)(wtLo + (size_t)Ll * 5 * 4096);
  int* offs   = counts + NR;
  int* cursor = offs + NR + 1;
  int* btot   = cursor + NR;
  int* elist  = (int*)((((uintptr_t)(btot + NBc)) + 15) & ~(uintptr_t)15);

  const int* src = ei;
  const int* dst = ei + Ee;

  hipMemsetAsync(counts, 0, (size_t)NR * sizeof(int), stream);

  // capture-safe host-side queries (no stream ops)
  int dev = 0;
  hipGetDevice(&dev);
  int mbpc = 0;
  hipError_t qe = hipOccupancyMaxActiveBlocksPerMultiprocessor(
      &mbpc, (const void*)k_mega, 128, 0);
  int ncu = 0;
  hipDeviceGetAttribute(&ncu, hipDeviceAttributeMultiprocessorCount, dev);
  long cap = (qe == hipSuccess && ncu > 0) ? (long)mbpc * (long)ncu : 0;

  if (cap >= 256) {
    int grid = (int)((cap < NT) ? cap : NT);
    void* ka[] = {
        (void*)&x, (void*)&src, (void*)&dst, (void*)&et, (void*)&batch,
        (void*)&selfW, (void*)&W1, (void*)&W2,
        (void*)&selfb, (void*)&eps, (void*)&b1, (void*)&b2,
        (void*)&l1W, (void*)&l1b, (void*)&l2W, (void*)&l2b,
        (void*)&hb0, (void*)&hb1, (void*)&wtHi, (void*)&wtLo,
        (void*)&counts, (void*)&offs, (void*)&cursor, (void*)&btot,
        (void*)&elist, (void*)&out};
    hipError_t le = hipLaunchCooperativeKernel((const void*)k_mega, dim3(grid),
                                               dim3(128), ka, 0, stream);
    if (le == hipSuccess) return;
  }

  // fallback: proven multi-kernel sequence (round 14)
  k_setup<<<CVT_B + PREP_B + HIST_B, 256, 0, stream>>>(
      x, hb0, selfW, W1, W2, wtHi, wtLo, dst, et, counts);
  k_scan1<<<NBc, 1024, 0, stream>>>(counts, offs, btot);
  k_scan3<<<NBc, 1024, 0, stream>>>(counts, btot, offs, cursor);
  k_fill<<<(Ee + 255) / 256, 256, 0, stream>>>(src, dst, et, cursor, elist);
  const unsigned short* hbc = hb0;
  unsigned short* hnb = hb1;
  for (int l = 0; l < Ll; ++l) {
    k_upd<<<NT, 128, 0, stream>>>(hbc, offs, counts, elist, wtHi, wtLo,
                                  selfb, eps, b1, b2, hnb, l);
    hbc = hnb;
    hnb = (hnb == hb0) ? hb1 : hb0;
  }
  k_poolhead<<<Gg, 512, 0, stream>>>(hbc, batch, l1W, l1b, l2W, l2b, out);
}

// Round 17
// 271.750 us; speedup vs baseline: 4.8139x; 4.8139x over previous
//
#include <hip/hip_runtime.h>

#define Nn 50000
#define Dd 64
#define Ee 800000
#define Ll 3
#define Rr 2
#define Gg 128
#define Cc 10
#define NR (Nn * Rr)
#define NBc 98                 // 1024-element scan chunks over NR
#define NT (Nn / 16)           // 3125 tasks

// k_setup block ranges (exact multiples of 256)
#define CVT_B  3125
#define PREP_B 240
#define HIST_B 3125

typedef __attribute__((ext_vector_type(8))) short short8;
typedef __attribute__((ext_vector_type(4))) float f32x4;

__device__ __forceinline__ unsigned short bf16_rne(float x) {
  unsigned u = __float_as_uint(x);
  unsigned r = u + 0x7fffu + ((u >> 16) & 1u);
  return (unsigned short)(r >> 16);
}
__device__ __forceinline__ float bf16_tof(unsigned short b) {
  return __uint_as_float(((unsigned)b) << 16);
}
__device__ __forceinline__ void acc8(float* z, uint4 u) {
  z[0] += __uint_as_float(u.x << 16);
  z[1] += __uint_as_float(u.x & 0xffff0000u);
  z[2] += __uint_as_float(u.y << 16);
  z[3] += __uint_as_float(u.y & 0xffff0000u);
  z[4] += __uint_as_float(u.z << 16);
  z[5] += __uint_as_float(u.z & 0xffff0000u);
  z[6] += __uint_as_float(u.w << 16);
  z[7] += __uint_as_float(u.w & 0xffff0000u);
}

#define WOFF(m, c, ks) ((size_t)(m)*4096 + (size_t)(c)*64 + (ks)*32 + koff)

// ---------------- one GIN layer task (identical math to round 14) -----------
__device__ __forceinline__ void layer_task(
    int task, const unsigned short* hb, unsigned short* hnb, int l,
    const int* offs, const int* counts, const int* elist,
    const unsigned short* wtHi, const unsigned short* wtLo,
    const float* selfb, const float* eps, const float* b1, const float* b2,
    unsigned short* tbh, unsigned short* tbl)
{
  float* xfer = (float*)tbh;            // aliased: tb dead by combine time
  const int wave = threadIdx.x >> 6;    // = relation r
  const int lane = threadIdx.x & 63;
  const int r = wave;
  const int idx15 = lane & 15;
  const int kg = lane >> 4;
  const int koff = kg * 8;
  const int nodeA = task * 16 + idx15;
  unsigned short* tw_h = tbh + wave * (16 * 72);
  unsigned short* tw_l = tbl + wave * (16 * 72);

  uint4 u0, u1;
  {
    const unsigned short* hp = &hb[(size_t)nodeA * 64 + koff];
    u0 = *(const uint4*)(hp);
    u1 = *(const uint4*)(hp + 32);
  }
  float f[2][8];
  f[0][0] = __uint_as_float(u0.x << 16); f[0][1] = __uint_as_float(u0.x & 0xffff0000u);
  f[0][2] = __uint_as_float(u0.y << 16); f[0][3] = __uint_as_float(u0.y & 0xffff0000u);
  f[0][4] = __uint_as_float(u0.z << 16); f[0][5] = __uint_as_float(u0.z & 0xffff0000u);
  f[0][6] = __uint_as_float(u0.w << 16); f[0][7] = __uint_as_float(u0.w & 0xffff0000u);
  f[1][0] = __uint_as_float(u1.x << 16); f[1][1] = __uint_as_float(u1.x & 0xffff0000u);
  f[1][2] = __uint_as_float(u1.y << 16); f[1][3] = __uint_as_float(u1.y & 0xffff0000u);
  f[1][4] = __uint_as_float(u1.z << 16); f[1][5] = __uint_as_float(u1.z & 0xffff0000u);
  f[1][6] = __uint_as_float(u1.w << 16); f[1][7] = __uint_as_float(u1.w & 0xffff0000u);

  const unsigned short* whi = wtHi + (size_t)l * 5 * 4096;
  const unsigned short* wlo = wtLo + (size_t)l * 5 * 4096;
  const int m1 = 1 + 2 * r, m2 = 2 + 2 * r;
  const float er = 1.0f + eps[l * Rr + r];

  float za[2][8];
#pragma unroll
  for (int ks = 0; ks < 2; ++ks)
#pragma unroll
    for (int jj = 0; jj < 8; ++jj) za[ks][jj] = 0.0f;
  {
    const int aidx = r * Nn + nodeA;
    const int jb = offs[aidx];
    const int je = jb + counts[aidx];
    int j = jb;
    if (j + 7 < je) {
      int4 ec0 = *(const int4*)&elist[j];
      int4 ec1 = *(const int4*)&elist[j + 4];
      for (; j + 7 < je; j += 8) {
        int4 en0 = *(const int4*)&elist[j + 8];
        int4 en1 = *(const int4*)&elist[j + 12];
        const unsigned short* q0 = &hb[(size_t)ec0.x * 64 + koff];
        const unsigned short* q1 = &hb[(size_t)ec0.y * 64 + koff];
        const unsigned short* q2 = &hb[(size_t)ec0.z * 64 + koff];
        const unsigned short* q3 = &hb[(size_t)ec0.w * 64 + koff];
        const unsigned short* q4 = &hb[(size_t)ec1.x * 64 + koff];
        const unsigned short* q5 = &hb[(size_t)ec1.y * 64 + koff];
        const unsigned short* q6 = &hb[(size_t)ec1.z * 64 + koff];
        const unsigned short* q7 = &hb[(size_t)ec1.w * 64 + koff];
        const uint4 a0 = *(const uint4*)(q0);
        const uint4 a1 = *(const uint4*)(q1);
        const uint4 a2 = *(const uint4*)(q2);
        const uint4 a3 = *(const uint4*)(q3);
        const uint4 a4 = *(const uint4*)(q4);
        const uint4 a5 = *(const uint4*)(q5);
        const uint4 a6 = *(const uint4*)(q6);
        const uint4 a7 = *(const uint4*)(q7);
        const uint4 b0 = *(const uint4*)(q0 + 32);
        const uint4 b1q = *(const uint4*)(q1 + 32);
        const uint4 b2q = *(const uint4*)(q2 + 32);
        const uint4 b3 = *(const uint4*)(q3 + 32);
        const uint4 b4 = *(const uint4*)(q4 + 32);
        const uint4 b5 = *(const uint4*)(q5 + 32);
        const uint4 b6 = *(const uint4*)(q6 + 32);
        const uint4 b7 = *(const uint4*)(q7 + 32);
        acc8(za[0], a0); acc8(za[0], a1); acc8(za[0], a2); acc8(za[0], a3);
        acc8(za[0], a4); acc8(za[0], a5); acc8(za[0], a6); acc8(za[0], a7);
        acc8(za[1], b0); acc8(za[1], b1q); acc8(za[1], b2q); acc8(za[1], b3);
        acc8(za[1], b4); acc8(za[1], b5); acc8(za[1], b6); acc8(za[1], b7);
        ec0 = en0; ec1 = en1;
      }
    }
    if (j + 3 < je) {
      int4 ec = *(const int4*)&elist[j];
      const unsigned short* q0 = &hb[(size_t)ec.x * 64 + koff];
      const unsigned short* q1 = &hb[(size_t)ec.y * 64 + koff];
      const unsigned short* q2 = &hb[(size_t)ec.z * 64 + koff];
      const unsigned short* q3 = &hb[(size_t)ec.w * 64 + koff];
      const uint4 a0 = *(const uint4*)(q0);
      const uint4 a1 = *(const uint4*)(q1);
      const uint4 a2 = *(const uint4*)(q2);
      const uint4 a3 = *(const uint4*)(q3);
      const uint4 b0 = *(const uint4*)(q0 + 32);
      const uint4 b1q = *(const uint4*)(q1 + 32);
      const uint4 b2q = *(const uint4*)(q2 + 32);
      const uint4 b3 = *(const uint4*)(q3 + 32);
      acc8(za[0], a0); acc8(za[0], a1); acc8(za[0], a2); acc8(za[0], a3);
      acc8(za[1], b0); acc8(za[1], b1q); acc8(za[1], b2q); acc8(za[1], b3);
      j += 4;
    }
    for (; j < je; ++j) {
      const unsigned short* q = &hb[(size_t)elist[j] * 64 + koff];
      const uint4 a = *(const uint4*)(q);
      const uint4 b = *(const uint4*)(q + 32);
      acc8(za[0], a); acc8(za[1], b);
    }
  }

  short8 zhi[2], zlo[2];
#pragma unroll
  for (int ks = 0; ks < 2; ++ks)
#pragma unroll
    for (int jj = 0; jj < 8; ++jj) {
      float zf = er * f[ks][jj] + za[ks][jj];
      unsigned short hb2 = bf16_rne(zf);
      zhi[ks][jj] = (short)hb2;
      zlo[ks][jj] = (short)bf16_rne(zf - bf16_tof(hb2));
    }

  f32x4 tacc[4];
#pragma unroll
  for (int cb = 0; cb < 4; ++cb) {
    float bi = b1[((size_t)l * 2 + r) * 64 + cb * 16 + idx15];
    tacc[cb] = (f32x4){bi, bi, bi, bi};
  }
#pragma unroll
  for (int cb = 0; cb < 4; ++cb) {
    int c = cb * 16 + idx15;
#pragma unroll
    for (int ks = 0; ks < 2; ++ks) {
      const short8 bh = *(const short8*)&whi[WOFF(m1, c, ks)];
      const short8 bl = *(const short8*)&wlo[WOFF(m1, c, ks)];
      tacc[cb] = __builtin_amdgcn_mfma_f32_16x16x32_bf16(zhi[ks], bh, tacc[cb], 0, 0, 0);
      tacc[cb] = __builtin_amdgcn_mfma_f32_16x16x32_bf16(zhi[ks], bl, tacc[cb], 0, 0, 0);
      tacc[cb] = __builtin_amdgcn_mfma_f32_16x16x32_bf16(zlo[ks], bh, tacc[cb], 0, 0, 0);
    }
  }
#pragma unroll
  for (int cb = 0; cb < 4; ++cb)
#pragma unroll
    for (int q = 0; q < 4; ++q) {
      float tv = fmaxf(tacc[cb][q], 0.0f);
      unsigned short hb2 = bf16_rne(tv);
      tw_h[(kg * 4 + q) * 72 + cb * 16 + idx15] = hb2;
      tw_l[(kg * 4 + q) * 72 + cb * 16 + idx15] = bf16_rne(tv - bf16_tof(hb2));
    }
  asm volatile("s_waitcnt lgkmcnt(0)" ::: "memory");
  __builtin_amdgcn_sched_barrier(0);
  short8 thi[2], tlo[2];
#pragma unroll
  for (int ks = 0; ks < 2; ++ks) {
    thi[ks] = *(const short8*)&tw_h[idx15 * 72 + ks * 32 + koff];
    tlo[ks] = *(const short8*)&tw_l[idx15 * 72 + ks * 32 + koff];
  }

  f32x4 facc[4];
#pragma unroll
  for (int cb = 0; cb < 4; ++cb) {
    int c = cb * 16 + idx15;
    float bi = b2[((size_t)l * 2 + r) * 64 + c];
    if (wave == 1) bi += selfb[l * 64 + c];
    facc[cb] = (f32x4){bi, bi, bi, bi};
  }
#pragma unroll
  for (int cb = 0; cb < 4; ++cb) {
    int c = cb * 16 + idx15;
#pragma unroll
    for (int ks = 0; ks < 2; ++ks) {
      const short8 bh = *(const short8*)&whi[WOFF(m2, c, ks)];
      const short8 bl = *(const short8*)&wlo[WOFF(m2, c, ks)];
      facc[cb] = __builtin_amdgcn_mfma_f32_16x16x32_bf16(thi[ks], bh, facc[cb], 0, 0, 0);
      facc[cb] = __builtin_amdgcn_mfma_f32_16x16x32_bf16(thi[ks], bl, facc[cb], 0, 0, 0);
      facc[cb] = __builtin_amdgcn_mfma_f32_16x16x32_bf16(tlo[ks], bh, facc[cb], 0, 0, 0);
    }
  }
  if (wave == 1) {
    short8 ahi[2];
    ahi[0][0] = (short)(u0.x & 0xffff); ahi[0][1] = (short)(u0.x >> 16);
    ahi[0][2] = (short)(u0.y & 0xffff); ahi[0][3] = (short)(u0.y >> 16);
    ahi[0][4] = (short)(u0.z & 0xffff); ahi[0][5] = (short)(u0.z >> 16);
    ahi[0][6] = (short)(u0.w & 0xffff); ahi[0][7] = (short)(u0.w >> 16);
    ahi[1][0] = (short)(u1.x & 0xffff); ahi[1][1] = (short)(u1.x >> 16);
    ahi[1][2] = (short)(u1.y & 0xffff); ahi[1][3] = (short)(u1.y >> 16);
    ahi[1][4] = (short)(u1.z & 0xffff); ahi[1][5] = (short)(u1.z >> 16);
    ahi[1][6] = (short)(u1.w & 0xffff); ahi[1][7] = (short)(u1.w >> 16);
#pragma unroll
    for (int cb = 0; cb < 4; ++cb) {
      int c = cb * 16 + idx15;
#pragma unroll
      for (int ks = 0; ks < 2; ++ks) {
        const short8 bh = *(const short8*)&whi[WOFF(0, c, ks)];
        const short8 bl = *(const short8*)&wlo[WOFF(0, c, ks)];
        facc[cb] = __builtin_amdgcn_mfma_f32_16x16x32_bf16(ahi[ks], bh, facc[cb], 0, 0, 0);
        facc[cb] = __builtin_amdgcn_mfma_f32_16x16x32_bf16(ahi[ks], bl, facc[cb], 0, 0, 0);
      }
    }
  }
  __syncthreads();                      // all tb reads done -> safe to alias
  if (wave == 1) {
#pragma unroll
    for (int cb = 0; cb < 4; ++cb)
#pragma unroll
      for (int q = 0; q < 4; ++q)
        xfer[(kg * 4 + q) * 65 + cb * 16 + idx15] = facc[cb][q];
  }
  __syncthreads();
  if (wave == 0) {
#pragma unroll
    for (int cb = 0; cb < 4; ++cb)
#pragma unroll
      for (int q = 0; q < 4; ++q) {
        int row = kg * 4 + q, col = cb * 16 + idx15;
        float v = facc[cb][q] + xfer[row * 65 + col];
        hnb[((size_t)task * 16 + row) * 64 + col] = bf16_rne(v);
      }
  }
}

// ========== fused setup: x->bf16 shadow | weight split-bf16 prep | hist =====
__global__ __launch_bounds__(256) void k_setup(
    const float* __restrict__ x, unsigned short* __restrict__ hb,
    const float* __restrict__ selfW, const float* __restrict__ W1,
    const float* __restrict__ W2, unsigned short* __restrict__ wtHi,
    unsigned short* __restrict__ wtLo,
    const int* __restrict__ dst, const int* __restrict__ et,
    int* __restrict__ counts)
{
  int b = blockIdx.x;
  if (b < CVT_B) {
    int i = b * 256 + threadIdx.x;
    const float4 v = *(const float4*)&x[(size_t)i * 4];
    ushort4 o;
    o.x = bf16_rne(v.x); o.y = bf16_rne(v.y);
    o.z = bf16_rne(v.z); o.w = bf16_rne(v.w);
    *(ushort4*)&hb[(size_t)i * 4] = o;
  } else if (b < CVT_B + PREP_B) {
    int i = (b - CVT_B) * 256 + threadIdx.x;
    int l = i / (5 * 4096);
    int rem = i - l * 5 * 4096;
    int m = rem >> 12;
    int e = rem & 4095;
    int k = e >> 6, c = e & 63;
    const float* p;
    if (m == 0)      p = selfW + (size_t)l * 4096;
    else if (m == 1) p = W1 + ((size_t)l * 2 + 0) * 4096;
    else if (m == 2) p = W2 + ((size_t)l * 2 + 0) * 4096;
    else if (m == 3) p = W1 + ((size_t)l * 2 + 1) * 4096;
    else             p = W2 + ((size_t)l * 2 + 1) * 4096;
    float w = p[e];
    unsigned short hi = bf16_rne(w);
    unsigned short lo = bf16_rne(w - bf16_tof(hi));
    size_t o = ((size_t)(l * 5 + m) * 64 + c) * 64 + k;
    wtHi[o] = hi;
    wtLo[o] = lo;
  } else {
    int e = (b - CVT_B - PREP_B) * 256 + threadIdx.x;
    atomicAdd(&counts[et[e] * Nn + dst[e]], 1);
  }
}

// ================= CSR scan + fill (segments padded to 4-int multiples) =====
__global__ __launch_bounds__(1024) void k_scan1(
    const int* __restrict__ counts, int* __restrict__ offs,
    int* __restrict__ btot)
{
  __shared__ int s[1024];
  int i = blockIdx.x * 1024 + threadIdx.x;
  int v = (i < NR) ? ((counts[i] + 3) & ~3) : 0;
  s[threadIdx.x] = v;
  __syncthreads();
#pragma unroll
  for (int d = 1; d < 1024; d <<= 1) {
    int t = (threadIdx.x >= d) ? s[threadIdx.x - d] : 0;
    __syncthreads();
    s[threadIdx.x] += t;
    __syncthreads();
  }
  if (i < NR) offs[i + 1] = s[threadIdx.x];
  if (threadIdx.x == 1023) btot[blockIdx.x] = s[1023];
}

__global__ __launch_bounds__(1024) void k_scan3(
    const int* __restrict__ counts, const int* __restrict__ btot,
    int* __restrict__ offs, int* __restrict__ cursor)
{
  __shared__ int bs[128];
  int v = (threadIdx.x < NBc) ? btot[threadIdx.x] : 0;
  if (threadIdx.x < 128) bs[threadIdx.x] = v;
  __syncthreads();
#pragma unroll
  for (int d = 1; d < 128; d <<= 1) {
    int t = (threadIdx.x >= d && threadIdx.x < 128) ? bs[threadIdx.x - d] : 0;
    __syncthreads();
    if (threadIdx.x < 128) bs[threadIdx.x] += t;
    __syncthreads();
  }
  int myb = (blockIdx.x == 0) ? 0 : bs[blockIdx.x - 1];
  int i = blockIdx.x * 1024 + threadIdx.x;
  if (i >= NR) return;
  int o = offs[i + 1] + myb;
  offs[i + 1] = o;
  cursor[i] = o - ((counts[i] + 3) & ~3);
  if (i == 0) offs[0] = 0;
}

__global__ __launch_bounds__(256) void k_fill(
    const int* __restrict__ src, const int* __restrict__ dst,
    const int* __restrict__ et, int* __restrict__ cursor,
    int* __restrict__ elist)
{
  int e = blockIdx.x * 256 + threadIdx.x;
  if (e >= Ee) return;
  int pos = atomicAdd(&cursor[et[e] * Nn + dst[e]], 1);
  elist[pos] = src[e];
}

__global__ __launch_bounds__(128, 4) void k_upd(
    const unsigned short* hb, const int* offs, const int* counts,
    const int* elist, const unsigned short* wtHi, const unsigned short* wtLo,
    const float* selfb, const float* eps, const float* b1, const float* b2,
    unsigned short* hnb, int l)
{
  __shared__ __align__(16) unsigned short tbh[2 * 16 * 72];
  __shared__ __align__(16) unsigned short tbl[2 * 16 * 72];
  layer_task(blockIdx.x, hb, hnb, l, offs, counts, elist, wtHi, wtLo,
             selfb, eps, b1, b2, tbh, tbl);
}

// ====== fused pool+head: 8 waves per graph, LDS combine, no atomics =========
__global__ __launch_bounds__(512) void k_poolhead(
    const unsigned short* __restrict__ hb, const int* __restrict__ batch,
    const float* __restrict__ l1W, const float* __restrict__ l1b,
    const float* __restrict__ l2W, const float* __restrict__ l2b,
    float* __restrict__ out)
{
  __shared__ float part[8][64];
  int g = blockIdx.x;
  int wave = threadIdx.x >> 6;
  int lane = threadIdx.x & 63;
  int lo = 0, hi = Nn;
  while (lo < hi) { int mid = (lo + hi) >> 1; if (batch[mid] < g) lo = mid + 1; else hi = mid; }
  int start = lo;
  hi = Nn;
  while (lo < hi) { int mid = (lo + hi) >> 1; if (batch[mid] < g + 1) lo = mid + 1; else hi = mid; }
  int end = lo;

  float acc = 0.0f;
  for (int i = start + wave; i < end; i += 8)
    acc += bf16_tof(hb[(size_t)i * 64 + lane]);
  part[wave][lane] = acc;
  __syncthreads();
  if (wave == 0) {
    float s = 0.0f;
#pragma unroll
    for (int w = 0; w < 8; ++w) s += part[w][lane];
    float p = s / fmaxf((float)(end - start), 1.0f);
    float t = l1b[lane];
#pragma unroll
    for (int k = 0; k < Dd; ++k)
      t += __shfl(p, k, 64) * l1W[k * Dd + lane];
    t = fmaxf(t, 0.0f);
    float o = (lane < Cc) ? l2b[lane] : 0.0f;
#pragma unroll
    for (int k = 0; k < Dd; ++k) {
      float w = (lane < Cc) ? l2W[k * Cc + lane] : 0.0f;
      o += __shfl(t, k, 64) * w;
    }
    if (lane < Cc) out[(size_t)g * Cc + lane] = o;
  }
}

extern "C" void kernel_launch(void* const* d_in, const int* in_sizes, int n_in,
                              void* d_out, int out_size, void* d_ws, size_t ws_size,
                              hipStream_t stream)
{
  const float* x     = (const float*)d_in[0];
  const int*   ei    = (const int*)d_in[1];
  const int*   et    = (const int*)d_in[2];
  const int*   batch = (const int*)d_in[3];
  const float* selfW = (const float*)d_in[4];
  const float* selfb = (const float*)d_in[5];
  const float* eps   = (const float*)d_in[6];
  const float* W1    = (const float*)d_in[7];
  const float* b1    = (const float*)d_in[8];
  const float* W2    = (const float*)d_in[9];
  const float* b2    = (const float*)d_in[10];
  const float* l1W   = (const float*)d_in[11];
  const float* l1b   = (const float*)d_in[12];
  const float* l2W   = (const float*)d_in[13];
  const float* l2b   = (const float*)d_in[14];
  float* out = (float*)d_out;

  unsigned short* hb0 = (unsigned short*)d_ws;
  unsigned short* hb1 = hb0 + (size_t)Nn * Dd;
  unsigned short* wtHi = hb1 + (size_t)Nn * Dd;
  unsigned short* wtLo = wtHi + (size_t)Ll * 5 * 4096;
  int* counts = (int*)(wtLo + (size_t)Ll * 5 * 4096);
  int* offs   = counts + NR;
  int* cursor = offs + NR + 1;
  int* btot   = cursor + NR;
  int* elist  = (int*)((((uintptr_t)(btot + NBc)) + 15) & ~(uintptr_t)15);

  const int* src = ei;
  const int* dst = ei + Ee;

  hipMemsetAsync(counts, 0, (size_t)NR * sizeof(int), stream);
  k_setup<<<CVT_B + PREP_B + HIST_B, 256, 0, stream>>>(
      x, hb0, selfW, W1, W2, wtHi, wtLo, dst, et, counts);
  k_scan1<<<NBc, 1024, 0, stream>>>(counts, offs, btot);
  k_scan3<<<NBc, 1024, 0, stream>>>(counts, btot, offs, cursor);
  k_fill<<<(Ee + 255) / 256, 256, 0, stream>>>(src, dst, et, cursor, elist);

  const unsigned short* hbc = hb0;
  unsigned short* hnb = hb1;
  for (int l = 0; l < Ll; ++l) {
    k_upd<<<NT, 128, 0, stream>>>(hbc, offs, counts, elist, wtHi, wtLo,
                                  selfb, eps, b1, b2, hnb, l);
    hbc = hnb;
    hnb = (hnb == hb0) ? hb1 : hb0;
  }
  k_poolhead<<<Gg, 512, 0, stream>>>(hbc, batch, l1W, l1b, l2W, l2b, out);
}